// Round 1
// baseline (56.509 us; speedup 1.0000x reference)
//
#include <hip/hip_runtime.h>

typedef __bf16 v8bf __attribute__((ext_vector_type(8)));
typedef float f32x4 __attribute__((ext_vector_type(4)));
typedef unsigned short u16x8 __attribute__((ext_vector_type(8)));

#define C_IN 256
#define HW   64
#define OHW  63
#define NOC  128

__device__ __forceinline__ unsigned short f2bf(float f) {
  unsigned u = __builtin_bit_cast(unsigned, f);
  unsigned r = u + 0x7FFFu + ((u >> 16) & 1u);   // round-to-nearest-even
  return (unsigned short)(r >> 16);
}

// Wf layout: [kp(4)][khkw(4)][cblk(32)][oc(128)][j(8)]  (bf16), 1 MiB total.
// A-fragment for mfma_f32_16x16x32_bf16: lane l reads 16B at
//   ((kp*4+khkw)*32 + cblk = c0/8 + (l>>4)) * 1024 + (oc0 + (l&15)) * 8
__global__ void wprep(const float* __restrict__ weight,
                      unsigned short* __restrict__ Wf) {
  int i = blockIdx.x * 256 + threadIdx.x;       // 524288 elements
  int j = i & 7;
  int t = i >> 3;
  int oc   = t & 127; t >>= 7;
  int cblk = t & 31;  t >>= 5;
  int khkw = t & 3;
  int kp   = t >> 2;
  int c = cblk * 8 + j;
  int f = oc * 4 + kp;                          // filter index in weight[:512]
  Wf[i] = f2bf(weight[(f * C_IN + c) * 4 + khkw]);
}

// Block: n x (4 output rows) x (64 w, padded) x 128 oc. 8 waves:
//   wave = (ocg = wid>>2) * 64 oc  x  parity class kp = wid&3 (ph=kp>>1, pw=kp&1)
// Per wave: 4 oc-frags x 4 pixel-frags (2 h-rows x 2 wb-halves), acc 4x4 f32x4.
__global__ __launch_bounds__(512, 2) void robin_main(
    const float* __restrict__ x, const unsigned short* __restrict__ Wf,
    const float* __restrict__ bias, float* __restrict__ out) {
  // LDS x tile: [dy(5)][wcol(66)][c(64)] bf16, row = 128B, swizzled
  __shared__ __align__(16) unsigned short xs[5 * 66 * 64];
  char* xsb = (char*)xs;

  const int tid  = threadIdx.x;
  const int lane = tid & 63;
  const int wid  = tid >> 6;
  const int hb   = blockIdx.x;       // 16
  const int n    = blockIdx.y;       // 16
  const int h0   = hb * 4;

  const int ocg  = wid >> 2;         // 0..1 -> 64 oc each
  const int kp   = wid & 3;          // parity class
  const int ph   = kp >> 1, pw = kp & 1;
  const int lcol = lane & 15;        // N-col (pixel) / A-row (oc)
  const int lg   = lane >> 4;        // k-octet group 0..3

  f32x4 acc[4][4];
  const f32x4 zero = {0.0f, 0.0f, 0.0f, 0.0f};
#pragma unroll
  for (int m = 0; m < 4; ++m)
#pragma unroll
    for (int f = 0; f < 4; ++f) acc[m][f] = zero;

  for (int q = 0; q < 4; ++q) {      // c-chunks of 64
    const int cbase = q * 64;
    if (q) __syncthreads();          // protect LDS reuse

    // ---- stage: x[n, cbase..+64, h0..h0+4, 0..63] -> LDS bf16 (swizzled) ----
    // unit u = (dy*8 + o)*66 + wcol : one 8-channel octet at one (dy,wcol)
    for (int u = tid; u < 5 * 8 * 66; u += 512) {
      int wcol = u % 66;
      int t2   = u / 66;
      int o    = t2 & 7;             // c-octet within chunk
      int dy   = t2 >> 3;            // 0..4
      int y    = h0 + dy;
      bool valid = (y < HW) & (wcol < HW);
      const float* xp = x + (((size_t)(n * C_IN + cbase + o * 8) * HW + y) * HW + wcol);
      u16x8 pk;
#pragma unroll
      for (int jj = 0; jj < 8; ++jj) {
        float v = valid ? xp[jj * (HW * HW)] : 0.0f;
        pk[jj] = f2bf(v);
      }
      int boff = ((dy * 66 + wcol) * 128 + o * 16) ^ (((wcol >> 1) & 7) << 4);
      *(u16x8*)(xsb + boff) = pk;
    }
    __syncthreads();

    // ---- compute: 8 K-steps (khkw x c-sub), 16 MFMA each ----
#pragma unroll
    for (int khkw = 0; khkw < 4; ++khkw) {
      const int kh = khkw >> 1, kw = khkw & 1;
#pragma unroll
      for (int s = 0; s < 2; ++s) {
        // A-frags (weights) from global (L2-resident, fragment-ordered)
        v8bf a[4];
        const unsigned short* wp =
            Wf + (((size_t)(kp * 4 + khkw) * 32 + (q * 8 + s * 4 + lg)) * 128 +
                  ocg * 64 + lcol) * 8;
#pragma unroll
        for (int m = 0; m < 4; ++m) a[m] = *(const v8bf*)(wp + m * 16 * 8);

        // B-frags (x) from LDS
        v8bf b[4];
#pragma unroll
        for (int r = 0; r < 2; ++r) {
          const int dy = 2 * r + ph + kh;        // 0..4
#pragma unroll
          for (int hh = 0; hh < 2; ++hh) {
            int wcol = 2 * (hh * 16 + lcol) + pw + kw;   // <= 65
            int boff = ((dy * 66 + wcol) * 128 + s * 64 + lg * 16) ^
                       (((wcol >> 1) & 7) << 4);
            b[r * 2 + hh] = *(const v8bf*)(xsb + boff);
          }
        }
#pragma unroll
        for (int m = 0; m < 4; ++m)
#pragma unroll
          for (int f = 0; f < 4; ++f)
            acc[m][f] = __builtin_amdgcn_mfma_f32_16x16x32_bf16(
                a[m], b[f], acc[m][f], 0, 0, 0);
      }
    }
  }

  // ---- epilogue: D layout col=lane&15 (pixel), row=(lane>>4)*4+reg (oc) ----
#pragma unroll
  for (int m = 0; m < 4; ++m) {
#pragma unroll
    for (int r = 0; r < 2; ++r) {
      const int h = h0 + 2 * r + ph;
#pragma unroll
      for (int hh = 0; hh < 2; ++hh) {
        const int w = 2 * (hh * 16 + lcol) + pw;
        f32x4 v = acc[m][r * 2 + hh];
        if (h < OHW && w < OHW) {
#pragma unroll
          for (int reg = 0; reg < 4; ++reg) {
            int oc = ocg * 64 + m * 16 + lg * 4 + reg;
            out[((size_t)(n * NOC + oc) * OHW + h) * OHW + w] =
                v[reg] + bias[oc * 4 + kp];
          }
        }
      }
    }
  }
}

extern "C" void kernel_launch(void* const* d_in, const int* in_sizes, int n_in,
                              void* d_out, int out_size, void* d_ws, size_t ws_size,
                              hipStream_t stream) {
  const float* x      = (const float*)d_in[0];
  const float* weight = (const float*)d_in[1];
  const float* bias   = (const float*)d_in[2];
  float* out          = (float*)d_out;
  unsigned short* Wf  = (unsigned short*)d_ws;   // 1 MiB fragment-ordered weights

  wprep<<<2048, 256, 0, stream>>>(weight, Wf);
  robin_main<<<dim3(16, 16), 512, 0, stream>>>(x, Wf, bias, out);
}

// Round 2
// 54.100 us; speedup vs baseline: 1.0445x; 1.0445x over previous
//
#include <hip/hip_runtime.h>

typedef __bf16 v8bf __attribute__((ext_vector_type(8)));
typedef float f32x4 __attribute__((ext_vector_type(4)));

#define C_IN 256
#define HW   64
#define OHW  63
#define NOC  128

__device__ __forceinline__ unsigned short f2bf(float f) {
  unsigned u = __builtin_bit_cast(unsigned, f);
  unsigned r = u + 0x7FFFu + ((u >> 16) & 1u);   // round-to-nearest-even
  return (unsigned short)(r >> 16);
}

// Wf layout: [kp(4)][khkw(4)][cblk(32)][oc(128)][j(8)] bf16, 1 MiB.
// One filter per block, float4 reads -> fully coalesced.
__global__ void wprep(const float* __restrict__ w, unsigned short* __restrict__ Wf) {
  int f = blockIdx.x;                 // 512 filters
  int c = threadIdx.x;                // 256 channels
  f32x4 v = *(const f32x4*)(w + (size_t)f * 1024 + c * 4);  // 4 khkw taps
  int oc = f >> 2, kp = f & 3;
#pragma unroll
  for (int khkw = 0; khkw < 4; ++khkw)
    Wf[(((size_t)(kp * 4 + khkw) * 32 + (c >> 3)) * 128 + oc) * 8 + (c & 7)] =
        f2bf(v[khkw]);
}

// Block: n x (4 out rows) x (64 w) x 128 oc, 512 thr (8 waves).
// wave = ocg(2) x kp(4).  acc 4 oc-frag x 4 px-frag.
// LDS x tile: [dy(5)][wpair(33)][par(2)][c(32)] bf16 = 128B rows, XOR-swizzled,
// double-buffered (2 x 21120 B). c-chunks of 32 (8 chunks), T14 pipeline:
// load chunk q+1 -> regs, compute q, barrier, ds_write, barrier.
__global__ __launch_bounds__(512, 2) void robin_main(
    const float* __restrict__ x, const unsigned short* __restrict__ Wf,
    const float* __restrict__ bias, float* __restrict__ out) {
  __shared__ __align__(16) unsigned short xs[2][5 * 33 * 64];
  char* xb0 = (char*)xs[0];
  char* xb1 = (char*)xs[1];

  const int tid  = threadIdx.x;
  const int lane = tid & 63;
  const int wid  = tid >> 6;
  const int hb   = blockIdx.x;       // 16
  const int n    = blockIdx.y;       // 16
  const int h0   = hb * 4;

  const int ocg  = wid >> 2;
  const int kp   = wid & 3;
  const int ph   = kp >> 1, pw = kp & 1;
  const int lcol = lane & 15;        // pixel col (B) / oc row (A)
  const int lg   = lane >> 4;        // k-octet group

  // zero-fill wpair=32 rows (x col 64 pad) once, both buffers
  if (tid < 80) {
    int g  = tid & 7;                // granule
    int t2 = tid >> 3;               // 0..9
    int dy = t2 % 5, bi = t2 / 5;
    f32x4 z = {0.f, 0.f, 0.f, 0.f};
    *(f32x4*)((bi ? xb1 : xb0) + (dy * 33 + 32) * 128 + g * 16) = z;
  }

  f32x4 acc[4][4];
#pragma unroll
  for (int m = 0; m < 4; ++m)
#pragma unroll
    for (int f = 0; f < 4; ++f) acc[m][f] = (f32x4){0.f, 0.f, 0.f, 0.f};

  const float* xbase = x + (size_t)n * C_IN * HW * HW;
  f32x4 xr[5];

  // ---- staging helpers (unrolled, static indices) ----
#define LOADQ(QQ)                                                              \
  {                                                                            \
    const int cbase = (QQ) * 32;                                               \
    _Pragma("unroll") for (int k = 0; k < 5; ++k) {                            \
      int v = k * 512 + tid;                                                   \
      int w4 = v & 15, c = (v >> 4) & 31, dy = v >> 9;                         \
      int y = h0 + dy;                                                         \
      if (y < HW)                                                              \
        xr[k] = *(const f32x4*)(xbase + ((size_t)(cbase + c) * HW + y) * HW +  \
                                w4 * 4);                                       \
      else                                                                     \
        xr[k] = (f32x4){0.f, 0.f, 0.f, 0.f};                                   \
    }                                                                          \
  }

#define STOREQ(QQ)                                                             \
  {                                                                            \
    char* xd = ((QQ) & 1) ? xb1 : xb0;                                         \
    _Pragma("unroll") for (int k = 0; k < 5; ++k) {                            \
      int v = k * 512 + tid;                                                   \
      int w4 = v & 15, c = (v >> 4) & 31, dy = v >> 9;                         \
      _Pragma("unroll") for (int j = 0; j < 4; ++j) {                          \
        int wcol = w4 * 4 + j;                                                 \
        int wp_  = wcol >> 1;                                                  \
        int boff = ((dy * 33 + wp_) * 128 + (wcol & 1) * 64 + c * 2) ^         \
                   ((wp_ & 7) << 4);                                           \
        *(unsigned short*)(xd + boff) = f2bf(xr[k][j]);                        \
      }                                                                        \
    }                                                                          \
  }

  // prologue
  LOADQ(0);
  STOREQ(0);
  __syncthreads();

  for (int q = 0; q < 8; ++q) {
    if (q < 7) LOADQ(q + 1);

    // ---- compute chunk q: K = 4 khkw x 32 ch, 4 K-steps x 16 MFMA ----
    {
      const char* xsb = (q & 1) ? xb1 : xb0;
#pragma unroll
      for (int khkw = 0; khkw < 4; ++khkw) {
        const int kh = khkw >> 1, kw = khkw & 1;
        v8bf a[4];
        const unsigned short* wp =
            Wf + (((size_t)(kp * 4 + khkw) * 32 + (q * 4 + lg)) * 128 +
                  ocg * 64 + lcol) * 8;
#pragma unroll
        for (int m = 0; m < 4; ++m) a[m] = *(const v8bf*)(wp + m * 16 * 8);

        v8bf b[4];
#pragma unroll
        for (int r = 0; r < 2; ++r) {
          const int dy = 2 * r + ph + kh;
#pragma unroll
          for (int hh = 0; hh < 2; ++hh) {
            int wcol = 2 * (hh * 16 + lcol) + pw + kw;   // <= 64
            int wp_  = wcol >> 1;
            int boff = ((dy * 33 + wp_) * 128 + (wcol & 1) * 64 + lg * 16) ^
                       ((wp_ & 7) << 4);
            b[r * 2 + hh] = *(const v8bf*)(xsb + boff);
          }
        }
#pragma unroll
        for (int m = 0; m < 4; ++m)
#pragma unroll
          for (int f = 0; f < 4; ++f)
            acc[m][f] = __builtin_amdgcn_mfma_f32_16x16x32_bf16(
                a[m], b[f], acc[m][f], 0, 0, 0);
      }
    }

    if (q < 7) {
      __syncthreads();     // all waves done reading buf[(q+1)&1] (at q-1)
      STOREQ(q + 1);
      __syncthreads();     // writes visible before compute(q+1)
    }
  }

  // ---- epilogue: D col=lane&15 (pixel), row=(lane>>4)*4+reg (oc) ----
#pragma unroll
  for (int m = 0; m < 4; ++m) {
#pragma unroll
    for (int r = 0; r < 2; ++r) {
      const int h = h0 + 2 * r + ph;
#pragma unroll
      for (int hh = 0; hh < 2; ++hh) {
        const int w = 2 * (hh * 16 + lcol) + pw;
        f32x4 v = acc[m][r * 2 + hh];
        if (h < OHW && w < OHW) {
#pragma unroll
          for (int reg = 0; reg < 4; ++reg) {
            int oc = ocg * 64 + m * 16 + lg * 4 + reg;
            out[((size_t)(n * NOC + oc) * OHW + h) * OHW + w] =
                v[reg] + bias[oc * 4 + kp];
          }
        }
      }
    }
  }
#undef LOADQ
#undef STOREQ
}

extern "C" void kernel_launch(void* const* d_in, const int* in_sizes, int n_in,
                              void* d_out, int out_size, void* d_ws, size_t ws_size,
                              hipStream_t stream) {
  const float* x      = (const float*)d_in[0];
  const float* weight = (const float*)d_in[1];
  const float* bias   = (const float*)d_in[2];
  float* out          = (float*)d_out;
  unsigned short* Wf  = (unsigned short*)d_ws;   // 1 MiB fragment-ordered weights

  wprep<<<512, 256, 0, stream>>>(weight, Wf);
  robin_main<<<dim3(16, 16), 512, 0, stream>>>(x, Wf, bias, out);
}

// Round 3
// 49.111 us; speedup vs baseline: 1.1506x; 1.1016x over previous
//
#include <hip/hip_runtime.h>

typedef __bf16 v8bf __attribute__((ext_vector_type(8)));
typedef float f32x4 __attribute__((ext_vector_type(4)));

#define C_IN 256
#define HW   64
#define OHW  63
#define NOC  128

// Wf layout: [kp(4)][khkw(4)][cblk(32)][oc(128)][j(8)] bf16, 1 MiB.
__global__ void wprep(const float* __restrict__ w, __bf16* __restrict__ Wf) {
  int f = blockIdx.x;                 // 512 filters
  int c = threadIdx.x;                // 256 channels
  f32x4 v = *(const f32x4*)(w + (size_t)f * 1024 + c * 4);  // 4 khkw taps
  int oc = f >> 2, kp = f & 3;
#pragma unroll
  for (int khkw = 0; khkw < 4; ++khkw)
    Wf[(((size_t)(kp * 4 + khkw) * 32 + (c >> 3)) * 128 + oc) * 8 + (c & 7)] =
        (__bf16)v[khkw];
}

// Block: n x (4 out rows) x (64 w) x 128 oc, 1024 thr (16 waves = 4/SIMD).
// wave = ocg(4: 32 oc each) x kp(4).  acc: 2 oc-frags x 4 px-frags.
// LDS x tile: [dy(5)][wpair(33)][par(2)][c(32)] bf16, XOR-swizzled, dbuf.
__global__ __launch_bounds__(1024, 4) void robin_main(
    const float* __restrict__ x, const __bf16* __restrict__ Wf,
    const float* __restrict__ bias, float* __restrict__ out) {
  __shared__ __align__(16) __bf16 xs[2][5 * 33 * 64];
  char* xb0 = (char*)xs[0];
  char* xb1 = (char*)xs[1];

  const int tid  = threadIdx.x;
  const int lane = tid & 63;
  const int wid  = tid >> 6;
  const int hb   = blockIdx.x;       // 16
  const int n    = blockIdx.y;       // 16
  const int h0   = hb * 4;

  const int ocg  = wid >> 2;         // 0..3 -> 32 oc each
  const int kp   = wid & 3;          // parity class
  const int ph   = kp >> 1, pw = kp & 1;
  const int lcol = lane & 15;        // pixel col (B) / oc row (A)
  const int lg   = lane >> 4;        // k-octet group

  // zero-fill wpair=32 pad rows, both buffers
  if (tid < 80) {
    int g  = tid & 7;
    int t2 = tid >> 3;
    int dy = t2 % 5, bi = t2 / 5;
    f32x4 z = {0.f, 0.f, 0.f, 0.f};
    *(f32x4*)((bi ? xb1 : xb0) + (dy * 33 + 32) * 128 + g * 16) = z;
  }

  f32x4 acc[2][4];
#pragma unroll
  for (int m = 0; m < 2; ++m)
#pragma unroll
    for (int f = 0; f < 4; ++f) acc[m][f] = (f32x4){0.f, 0.f, 0.f, 0.f};

  const float* xbase = x + (size_t)n * C_IN * HW * HW;
  f32x4 xr[3];

  // 2560 float4 units per chunk: unit v -> dy=v>>9, c=(v>>4)&31, w4=v&15
#define LOADQ(QQ)                                                              \
  {                                                                            \
    const int cbase = (QQ) * 32;                                               \
    _Pragma("unroll") for (int k = 0; k < 3; ++k) {                            \
      int v = k * 1024 + tid;                                                  \
      if (v < 2560) {                                                          \
        int w4 = v & 15, c = (v >> 4) & 31, dy = v >> 9;                       \
        int y = h0 + dy;                                                       \
        if (y < HW)                                                            \
          xr[k] = *(const f32x4*)(xbase + ((size_t)(cbase + c) * HW + y) * HW +\
                                  w4 * 4);                                     \
        else                                                                   \
          xr[k] = (f32x4){0.f, 0.f, 0.f, 0.f};                                 \
      }                                                                        \
    }                                                                          \
  }

#define STOREQ(QQ)                                                             \
  {                                                                            \
    char* xd = ((QQ) & 1) ? xb1 : xb0;                                         \
    _Pragma("unroll") for (int k = 0; k < 3; ++k) {                            \
      int v = k * 1024 + tid;                                                  \
      if (v < 2560) {                                                          \
        int w4 = v & 15, c = (v >> 4) & 31, dy = v >> 9;                       \
        _Pragma("unroll") for (int j = 0; j < 4; ++j) {                        \
          int wcol = w4 * 4 + j;                                               \
          int wp_  = wcol >> 1;                                                \
          int boff = ((dy * 33 + wp_) * 128 + (wcol & 1) * 64 + c * 2) ^       \
                     ((wp_ & 7) << 4);                                         \
          *(__bf16*)(xd + boff) = (__bf16)xr[k][j];                            \
        }                                                                      \
      }                                                                        \
    }                                                                          \
  }

  // prologue
  LOADQ(0);
  STOREQ(0);
  __syncthreads();

  for (int q = 0; q < 8; ++q) {
    if (q < 7) LOADQ(q + 1);

    // ---- compute chunk q: 4 khkw K-steps x 8 MFMA ----
    {
      const char* xsb = (q & 1) ? xb1 : xb0;
#pragma unroll
      for (int khkw = 0; khkw < 4; ++khkw) {
        const int kh = khkw >> 1, kw = khkw & 1;
        v8bf a[2];
        const __bf16* wp =
            Wf + (((size_t)(kp * 4 + khkw) * 32 + (q * 4 + lg)) * 128 +
                  ocg * 32 + lcol) * 8;
#pragma unroll
        for (int m = 0; m < 2; ++m) a[m] = *(const v8bf*)(wp + m * 16 * 8);

        v8bf b[4];
#pragma unroll
        for (int r = 0; r < 2; ++r) {
          const int dy = 2 * r + ph + kh;
#pragma unroll
          for (int hh = 0; hh < 2; ++hh) {
            int wcol = 2 * (hh * 16 + lcol) + pw + kw;   // <= 64
            int wp_  = wcol >> 1;
            int boff = ((dy * 33 + wp_) * 128 + (wcol & 1) * 64 + lg * 16) ^
                       ((wp_ & 7) << 4);
            b[r * 2 + hh] = *(const v8bf*)(xsb + boff);
          }
        }
#pragma unroll
        for (int m = 0; m < 2; ++m)
#pragma unroll
          for (int f = 0; f < 4; ++f)
            acc[m][f] = __builtin_amdgcn_mfma_f32_16x16x32_bf16(
                a[m], b[f], acc[m][f], 0, 0, 0);
      }
    }

    if (q < 7) {
      __syncthreads();
      STOREQ(q + 1);
      __syncthreads();
    }
  }

  // ---- epilogue: D col=lane&15 (pixel), row=(lane>>4)*4+reg (oc) ----
#pragma unroll
  for (int m = 0; m < 2; ++m) {
#pragma unroll
    for (int r = 0; r < 2; ++r) {
      const int h = h0 + 2 * r + ph;
#pragma unroll
      for (int hh = 0; hh < 2; ++hh) {
        const int w = 2 * (hh * 16 + lcol) + pw;
        f32x4 v = acc[m][r * 2 + hh];
        if (h < OHW && w < OHW) {
#pragma unroll
          for (int reg = 0; reg < 4; ++reg) {
            int oc = ocg * 32 + m * 16 + lg * 4 + reg;
            out[((size_t)(n * NOC + oc) * OHW + h) * OHW + w] =
                v[reg] + bias[oc * 4 + kp];
          }
        }
      }
    }
  }
#undef LOADQ
#undef STOREQ
}

extern "C" void kernel_launch(void* const* d_in, const int* in_sizes, int n_in,
                              void* d_out, int out_size, void* d_ws, size_t ws_size,
                              hipStream_t stream) {
  const float* x      = (const float*)d_in[0];
  const float* weight = (const float*)d_in[1];
  const float* bias   = (const float*)d_in[2];
  float* out          = (float*)d_out;
  __bf16* Wf          = (__bf16*)d_ws;   // 1 MiB fragment-ordered weights

  wprep<<<512, 256, 0, stream>>>(weight, Wf);
  robin_main<<<dim3(16, 16), 1024, 0, stream>>>(x, Wf, bias, out);
}